// Round 5
// baseline (398.195 us; speedup 1.0000x reference)
//
#include <hip/hip_runtime.h>
#include <hip/hip_bf16.h>
#include <math.h>

typedef unsigned short u16;
typedef unsigned int   u32;
typedef __attribute__((ext_vector_type(8))) short short8;   // 8 bf16
typedef __attribute__((ext_vector_type(4))) float f32x4;    // MFMA acc

// Problem constants
constexpr int G  = 8;
constexpr int D  = 128;
constexpr int H  = 256;
constexpr int DM = 1024;
constexpr int PK = 1024;
constexpr int NTOK = 8 * 2048;   // 16384

// ---------- scalar helpers ----------
__device__ __forceinline__ float bf2f(u16 u) {
    union { u32 i; float f; } v; v.i = ((u32)u) << 16; return v.f;
}
__device__ __forceinline__ u16 f2bf(float f) {
    union { float f; u32 i; } v; v.f = f;
    u32 x = v.i;
    return (u16)((x + 0x7fffu + ((x >> 16) & 1u)) >> 16);  // RNE
}
__device__ __forceinline__ float f4c(const float4 v, int j) {
    return j == 0 ? v.x : j == 1 ? v.y : j == 2 ? v.z : v.w;
}
template <bool ISBF>
__device__ __forceinline__ float ld1(const void* p, size_t i) {
    if (ISBF) return bf2f(((const u16*)p)[i]);
    else      return ((const float*)p)[i];
}
template <bool ISBF>
__device__ __forceinline__ float4 ld4(const void* p, size_t i) {  // i % 4 == 0
    if (ISBF) {
        ushort4 v = *(const ushort4*)((const u16*)p + i);
        return make_float4(bf2f(v.x), bf2f(v.y), bf2f(v.z), bf2f(v.w));
    } else {
        return *(const float4*)((const float*)p + i);
    }
}
template <bool ISBF>
__device__ __forceinline__ void st4(void* p, size_t i, float4 v) {
    if (ISBF) {
        ushort4 o; o.x = f2bf(v.x); o.y = f2bf(v.y); o.z = f2bf(v.z); o.w = f2bf(v.w);
        *(ushort4*)((u16*)p + i) = o;
    } else {
        *(float4*)((float*)p + i) = v;
    }
}
// tanh-form GELU (max dev vs exact erf-GELU ~3e-4, tolerance 6.4e-2)
__device__ __forceinline__ float gelu_f(float v) {
    float u = v * (0.7978845608028654f + 0.0356774081f * v * v);
    float e = __expf(2.f * u);
    float th = 1.f - 2.f / (e + 1.f);
    return 0.5f * v * (1.f + th);
}
// async global->LDS, 16B per lane; lds base must be wave-uniform (dest = base + lane*16)
__device__ __forceinline__ void gl_lds16(const void* g, void* l) {
    __builtin_amdgcn_global_load_lds(
        (const __attribute__((address_space(1))) unsigned int*)g,
        (__attribute__((address_space(3))) unsigned int*)l, 16, 0, 0);
}

// ---------- dtype detect (proven R2) ----------
__global__ void detect_dtype(const void* xraw, int* flag) {
    __shared__ int cnt[256];
    const u32* xw = (const u32*)xraw;
    int tid = threadIdx.x, c = 0;
#pragma unroll
    for (int k = 0; k < 4; ++k) {
        u32 w = xw[tid * 4 + k];
#pragma unroll
        for (int h = 0; h < 2; ++h) {
            u16 u = (u16)(w >> (16 * h));
            int e = (u >> 7) & 0xFF;
            if ((u & 0x7FFF) == 0 || (e >= 112 && e <= 143)) ++c;
        }
    }
    cnt[tid] = c;
    __syncthreads();
    for (int s = 128; s > 0; s >>= 1) {
        if (tid < s) cnt[tid] += cnt[tid + s];
        __syncthreads();
    }
    if (tid == 0) flag[0] = (cnt[0] >= 1900) ? 1 : 0;
}

// ---------- conv weight prep: w1b[tap][h][d] ; w2b[tap][d][h] (bf16) ----------
template <bool ISBF>
__global__ void prep_mfma(const void* __restrict__ w1, const void* __restrict__ w2,
                          u16* __restrict__ w1b, u16* __restrict__ w2b,
                          const int* __restrict__ flag) {
    if ((flag[0] != 0) != ISBF) return;
    int idx = blockIdx.x * 256 + threadIdx.x;
    if (idx < 3 * H * D) {
        int k = idx / (H * D); int r = idx % (H * D); int h = r / D; int d = r % D;
        w1b[idx] = f2bf(ld1<ISBF>(w1, (size_t)(h * D + d) * 3 + k));
    }
    if (idx < 3 * D * H) {
        int k = idx / (D * H); int r = idx % (D * H); int d = r / H; int h = r % H;
        w2b[idx] = f2bf(ld1<ISBF>(w2, (size_t)(d * H + h) * 3 + k));
    }
}

// ---------- Wm transpose via LDS tiles: wmt[n][k] = Wm[k][n] (bf16) ----------
template <bool ISBF>
__global__ void trans_wm(const void* __restrict__ Wm, u16* __restrict__ wmt,
                         const int* __restrict__ flag) {
    if ((flag[0] != 0) != ISBF) return;
    __shared__ u16 tile[64][65];
    const int bx = blockIdx.x & 15, by = blockIdx.x >> 4;
    const int k0 = by * 64, n0 = bx * 64;
    const int rr = threadIdx.x >> 4;          // 0..15
    const int cc = (threadIdx.x & 15) * 4;    // 0..60
#pragma unroll
    for (int i = 0; i < 4; ++i) {
        int r = rr + i * 16;
        float4 v = ld4<ISBF>(Wm, (size_t)(k0 + r) * DM + n0 + cc);
        tile[r][cc + 0] = f2bf(v.x); tile[r][cc + 1] = f2bf(v.y);
        tile[r][cc + 2] = f2bf(v.z); tile[r][cc + 3] = f2bf(v.w);
    }
    __syncthreads();
#pragma unroll
    for (int i = 0; i < 4; ++i) {
        int r = rr + i * 16;                  // output row = n index
        ushort4 o;
        o.x = tile[cc + 0][r]; o.y = tile[cc + 1][r];
        o.z = tile[cc + 2][r]; o.w = tile[cc + 3][r];
        *(ushort4*)(wmt + (size_t)(n0 + r) * DM + k0 + cc) = o;
    }
}

// ---------- fused gate+LN1+conv1+GELU+conv2+LN2 -> z (bf16) ----------
// 4 tokens/block, 256 threads (4 waves), 16x16x32 bf16 MFMA, 4 blocks/CU.
constexpr int TPB = 4;
constexpr int XS  = 136;   // xnpad row stride (u16): 68 words = 4 mod 32 -> bank spread
constexpr int MS  = 264;   // midpad row stride: 132 words = 4 mod 32
constexpr int RS  = 132;   // residb row stride per g: 66 words = 2 mod 32, 8B-aligned rows

template <bool ISBF>
__global__ __launch_bounds__(256, 4)
void conv_fused(const void* __restrict__ x,
                const void* __restrict__ slot_gate,
                const void* __restrict__ slot_bias,
                const void* __restrict__ pre_g,
                const void* __restrict__ pre_b,
                const void* __restrict__ b1,
                const void* __restrict__ b2,
                const void* __restrict__ pack_g,
                const void* __restrict__ pack_b,
                const u16* __restrict__ w1b,
                const u16* __restrict__ w2b,
                u16* __restrict__ zout,
                const int* __restrict__ flag) {
    if ((flag[0] != 0) != ISBF) return;

    __shared__ u16 xnpad[TPB * 10 * XS];    // 10880 B
    __shared__ u16 midpad[TPB * 10 * MS];   // 21120 B
    __shared__ u16 residb[TPB * 8 * RS];    // 8448 B
    __shared__ float red_s[TPB][4], red_ss[TPB][4];

    const int tid  = threadIdx.x;
    const int lane = tid & 63, w = tid >> 6;
    const int quad = lane >> 4, col = lane & 15;
    const size_t tok0 = (size_t)blockIdx.x * TPB;

    // ---- zero pad rows (rows t*10+0 and t*10+9) ----
    {
        int r = tid >> 5, c4 = (tid & 31) * 4;   // 8 pad rows x 128 cols
        int t = r >> 1, wh = r & 1;
        *(ushort4*)&xnpad[(t * 10 + wh * 9) * XS + c4] = make_ushort4(0, 0, 0, 0);
        int c8 = (tid & 31) * 8;                 // 8 pad rows x 256 cols
        u16* p = &midpad[(t * 10 + wh * 9) * MS + c8];
        *(ushort4*)p = make_ushort4(0, 0, 0, 0);
        *(ushort4*)(p + 4) = make_ushort4(0, 0, 0, 0);
    }

    // ---- stage-1 per-thread params (e0 slice) ----
    const int e0 = 4 * tid;
    const int d0 = e0 & (D - 1);
    const int g0 = tid >> 5;
    float gf[4], bff[4], pgf[4], pbf[4];
    {
        float4 sg4 = ld4<ISBF>(slot_gate, e0);
        float4 sb4 = ld4<ISBF>(slot_bias, e0);
        float4 pg4 = ld4<ISBF>(pre_g, d0);
        float4 pb4 = ld4<ISBF>(pre_b, d0);
#pragma unroll
        for (int j = 0; j < 4; ++j) {
            gf[j]  = 2.f / (1.f + __expf(-f4c(sg4, j)));
            bff[j] = f4c(sb4, j);
            pgf[j] = f4c(pg4, j);
            pbf[j] = f4c(pb4, j);
        }
    }

    // ---- stage 1: gate+bias -> residb(bf16), LN1 -> xnpad(bf16) ----
    for (int t = 0; t < TPB; ++t) {
        float4 x4 = ld4<ISBF>(x, (tok0 + t) * PK + e0);
        float v[4];
#pragma unroll
        for (int j = 0; j < 4; ++j) v[j] = f4c(x4, j) * gf[j] + bff[j];
        ushort4 rb;
        rb.x = f2bf(v[0]); rb.y = f2bf(v[1]); rb.z = f2bf(v[2]); rb.w = f2bf(v[3]);
        *(ushort4*)&residb[(t * 8 + g0) * RS + d0] = rb;

        float s = v[0] + v[1] + v[2] + v[3];
        float ss = v[0]*v[0] + v[1]*v[1] + v[2]*v[2] + v[3]*v[3];
#pragma unroll
        for (int m = 1; m < 32; m <<= 1) {
            s  += __shfl_xor(s,  m);
            ss += __shfl_xor(ss, m);
        }
        float mean = s * (1.f / 128.f);
        float var  = ss * (1.f / 128.f) - mean * mean;
        float rstd = rsqrtf(var + 1e-5f);
        ushort4 o;
        o.x = f2bf((v[0] - mean) * rstd * pgf[0] + pbf[0]);
        o.y = f2bf((v[1] - mean) * rstd * pgf[1] + pbf[1]);
        o.z = f2bf((v[2] - mean) * rstd * pgf[2] + pbf[2]);
        o.w = f2bf((v[3] - mean) * rstd * pgf[3] + pbf[3]);
        *(ushort4*)&xnpad[(t * 10 + g0 + 1) * XS + d0] = o;
    }
    __syncthreads();

    // per-lane (t,g) row bases for the 2 N-tiles
    int rowb[2];
#pragma unroll
    for (int nt = 0; nt < 2; ++nt) {
        int n = nt * 16 + col;
        rowb[nt] = (n >> 3) * 10 + (n & 7);
    }
    const int kq = quad * 8;

    // ---- stage 2: conv1 via MFMA (C[h][(t,g)]) + bias + GELU -> midpad ----
    {
        f32x4 acc1[4][2] = {};   // [mtl][nt]
        for (int ktap = 0; ktap < 3; ++ktap) {
#pragma unroll
            for (int kk = 0; kk < 4; ++kk) {
                short8 bfr[2];
#pragma unroll
                for (int nt = 0; nt < 2; ++nt)
                    bfr[nt] = *(const short8*)&xnpad[(rowb[nt] + ktap) * XS + kk * 32 + kq];
#pragma unroll
                for (int mtl = 0; mtl < 4; ++mtl) {
                    int h = w * 64 + mtl * 16 + col;
                    short8 afr = *(const short8*)(w1b + (size_t)(ktap * H + h) * D + kk * 32 + kq);
#pragma unroll
                    for (int nt = 0; nt < 2; ++nt)
                        acc1[mtl][nt] = __builtin_amdgcn_mfma_f32_16x16x32_bf16(
                            afr, bfr[nt], acc1[mtl][nt], 0, 0, 0);
                }
            }
        }
#pragma unroll
        for (int mtl = 0; mtl < 4; ++mtl) {
            int hq = w * 64 + mtl * 16 + quad * 4;
            float4 b1q = ld4<ISBF>(b1, hq);
#pragma unroll
            for (int nt = 0; nt < 2; ++nt) {
                int n = nt * 16 + col; int t = n >> 3, g = n & 7;
                ushort4 o;
                o.x = f2bf(gelu_f(acc1[mtl][nt][0] + b1q.x));
                o.y = f2bf(gelu_f(acc1[mtl][nt][1] + b1q.y));
                o.z = f2bf(gelu_f(acc1[mtl][nt][2] + b1q.z));
                o.w = f2bf(gelu_f(acc1[mtl][nt][3] + b1q.w));
                *(ushort4*)&midpad[(t * 10 + g + 1) * MS + hq] = o;
            }
        }
    }
    __syncthreads();

    // ---- stage 3: conv2 via MFMA (C[d][(t,g)]) + bias + resid + LN2 + pack -> z ----
    {
        f32x4 acc2[2][2] = {};   // [mtl][nt]
        for (int ktap = 0; ktap < 3; ++ktap) {
#pragma unroll
            for (int kk = 0; kk < 8; ++kk) {
                short8 bfr[2];
#pragma unroll
                for (int nt = 0; nt < 2; ++nt)
                    bfr[nt] = *(const short8*)&midpad[(rowb[nt] + ktap) * MS + kk * 32 + kq];
#pragma unroll
                for (int mtl = 0; mtl < 2; ++mtl) {
                    int d = w * 32 + mtl * 16 + col;
                    short8 afr = *(const short8*)(w2b + (size_t)(ktap * D + d) * H + kk * 32 + kq);
#pragma unroll
                    for (int nt = 0; nt < 2; ++nt)
                        acc2[mtl][nt] = __builtin_amdgcn_mfma_f32_16x16x32_bf16(
                            afr, bfr[nt], acc2[mtl][nt], 0, 0, 0);
                }
            }
        }
        float vals[2][2][4];
        float s[2] = {0.f, 0.f}, ss[2] = {0.f, 0.f};
#pragma unroll
        for (int mtl = 0; mtl < 2; ++mtl) {
            int dq = w * 32 + mtl * 16 + quad * 4;
            float4 b2q = ld4<ISBF>(b2, dq);
#pragma unroll
            for (int nt = 0; nt < 2; ++nt) {
                int n = nt * 16 + col; int t = n >> 3, g = n & 7;
                ushort4 rb = *(const ushort4*)&residb[(t * 8 + g) * RS + dq];
#pragma unroll
                for (int r = 0; r < 4; ++r) {
                    float resid = bf2f(((const u16*)&rb)[r]);
                    float val = acc2[mtl][nt][r] + f4c(b2q, r) + resid;
                    vals[mtl][nt][r] = val;
                    s[nt] += val; ss[nt] += val * val;
                }
            }
        }
        // reduce over lanes sharing token: col bits 0-2 (g) + quad bits 4-5 (d)
#pragma unroll
        for (int nt = 0; nt < 2; ++nt) {
            s[nt] += __shfl_xor(s[nt], 1);  ss[nt] += __shfl_xor(ss[nt], 1);
            s[nt] += __shfl_xor(s[nt], 2);  ss[nt] += __shfl_xor(ss[nt], 2);
            s[nt] += __shfl_xor(s[nt], 4);  ss[nt] += __shfl_xor(ss[nt], 4);
            s[nt] += __shfl_xor(s[nt], 16); ss[nt] += __shfl_xor(ss[nt], 16);
            s[nt] += __shfl_xor(s[nt], 32); ss[nt] += __shfl_xor(ss[nt], 32);
        }
        if (quad == 0 && (col & 7) == 0) {
#pragma unroll
            for (int nt = 0; nt < 2; ++nt) {
                int t = 2 * nt + (col >> 3);
                red_s[t][w] = s[nt]; red_ss[t][w] = ss[nt];
            }
        }
        __syncthreads();
        float mean[2], rstd[2];
#pragma unroll
        for (int nt = 0; nt < 2; ++nt) {
            int t = 2 * nt + (col >> 3);
            float st  = red_s[t][0] + red_s[t][1] + red_s[t][2] + red_s[t][3];
            float sst = red_ss[t][0] + red_ss[t][1] + red_ss[t][2] + red_ss[t][3];
            mean[nt] = st * (1.f / 1024.f);
            float var = sst * (1.f / 1024.f) - mean[nt] * mean[nt];
            rstd[nt] = rsqrtf(var + 1e-5f);
        }
#pragma unroll
        for (int mtl = 0; mtl < 2; ++mtl) {
            int dq = w * 32 + mtl * 16 + quad * 4;
#pragma unroll
            for (int nt = 0; nt < 2; ++nt) {
                int n = nt * 16 + col; int t = n >> 3, g = n & 7;
                int e = g * D + dq;
                float4 pg = ld4<ISBF>(pack_g, e);
                float4 pb = ld4<ISBF>(pack_b, e);
                ushort4 o;
#pragma unroll
                for (int r = 0; r < 4; ++r) {
                    float z = (vals[mtl][nt][r] - mean[nt]) * rstd[nt] * f4c(pg, r) + f4c(pb, r);
                    ((u16*)&o)[r] = f2bf(z);
                }
                *(ushort4*)(zout + (tok0 + t) * PK + e) = o;
            }
        }
    }
}

// ---------- z @ WmT + bm via MFMA, 128x128 tiles, global_load_lds staging ----------
template <bool ISBF>
__global__ __launch_bounds__(256, 4)
void gemm_out(const u16* __restrict__ z, const u16* __restrict__ wmt,
              const void* __restrict__ bm, void* __restrict__ out,
              const int* __restrict__ flag) {
    if ((flag[0] != 0) != ISBF) return;
    __shared__ u16 As[128 * 32];   // z tile   [m][k] unpadded (64B rows)
    __shared__ u16 Bs[128 * 32];   // WmT tile [n][k]
    const int tid = threadIdx.x, lane = tid & 63, w = tid >> 6;
    const int quad = lane >> 4, col = lane & 15;
    const int bm0 = (blockIdx.x >> 3) * 128, bn0 = (blockIdx.x & 7) * 128;
    const int wm = w >> 1, wn = w & 1;
    f32x4 acc[4][4] = {};   // [nt][mt]

    // staging map: wave w covers rows [w*32, w*32+32), 2 calls x 16 rows each;
    // lane l -> row + (l>>2), 16B chunk (l&3)
    const int srow = (lane >> 2);
    const int scol = (lane & 3) * 8;

    for (int k0 = 0; k0 < DM; k0 += 32) {
        __syncthreads();
#pragma unroll
        for (int c = 0; c < 2; ++c) {
            int r = w * 32 + c * 16;
            gl_lds16(z   + (size_t)(bm0 + r + srow) * DM + k0 + scol, &As[r * 32]);
            gl_lds16(wmt + (size_t)(bn0 + r + srow) * DM + k0 + scol, &Bs[r * 32]);
        }
        __syncthreads();
        short8 zfr[4], wfr[4];
#pragma unroll
        for (int mt = 0; mt < 4; ++mt)
            zfr[mt] = *(const short8*)&As[(wm * 64 + mt * 16 + col) * 32 + quad * 8];
#pragma unroll
        for (int nt = 0; nt < 4; ++nt)
            wfr[nt] = *(const short8*)&Bs[(wn * 64 + nt * 16 + col) * 32 + quad * 8];
#pragma unroll
        for (int nt = 0; nt < 4; ++nt)
#pragma unroll
            for (int mt = 0; mt < 4; ++mt)
                acc[nt][mt] = __builtin_amdgcn_mfma_f32_16x16x32_bf16(
                    wfr[nt], zfr[mt], acc[nt][mt], 0, 0, 0);
    }
    // epilogue: C rows = n (quad*4+r), cols = m
#pragma unroll
    for (int nt = 0; nt < 4; ++nt) {
        int n = bn0 + wn * 64 + nt * 16 + quad * 4;
        float4 bq = ld4<ISBF>(bm, n);
#pragma unroll
        for (int mt = 0; mt < 4; ++mt) {
            int m = bm0 + wm * 64 + mt * 16 + col;
            float4 o = make_float4(acc[nt][mt][0] + bq.x, acc[nt][mt][1] + bq.y,
                                   acc[nt][mt][2] + bq.z, acc[nt][mt][3] + bq.w);
            st4<ISBF>(out, (size_t)m * DM + n, o);
        }
    }
}

// ---------- scalar fallback (R2-proven), raw weights ----------
template <bool ISBF>
__global__ __launch_bounds__(256)
void slotconv_scalar(const void* __restrict__ x,
                     const void* __restrict__ slot_gate,
                     const void* __restrict__ slot_bias,
                     const void* __restrict__ pre_g,
                     const void* __restrict__ pre_b,
                     const void* __restrict__ w1raw,
                     const void* __restrict__ b1,
                     const void* __restrict__ w2raw,
                     const void* __restrict__ b2,
                     const void* __restrict__ pack_g,
                     const void* __restrict__ pack_b,
                     const void* __restrict__ Wm,
                     const void* __restrict__ bm,
                     void* __restrict__ out,
                     const int* __restrict__ flag) {
    if ((flag[0] != 0) != ISBF) return;
    __shared__ float resid[G * D];
    __shared__ float xnpad[(G + 2) * D];
    __shared__ float midpadf[(G + 2) * H];
    __shared__ float zbuf[4][PK];
    __shared__ float red[8];
    const int tid = threadIdx.x;
    if (tid < D) { xnpad[tid] = 0.f; xnpad[(G + 1) * D + tid] = 0.f; }
    midpadf[tid] = 0.f; midpadf[(G + 1) * H + tid] = 0.f;
    const int e0 = 4 * tid;
    const int d0 = e0 & (D - 1);
    const int g0 = tid >> 5;
    float gate[4], bias[4], pgf[4], pbf[4];
    {
        float4 sg4 = ld4<ISBF>(slot_gate, e0);
        float4 sb4 = ld4<ISBF>(slot_bias, e0);
        float4 pg4 = ld4<ISBF>(pre_g, d0);
        float4 pb4 = ld4<ISBF>(pre_b, d0);
#pragma unroll
        for (int j = 0; j < 4; ++j) {
            gate[j] = 2.f / (1.f + __expf(-f4c(sg4, j)));
            bias[j] = f4c(sb4, j);
            pgf[j] = f4c(pg4, j); pbf[j] = f4c(pb4, j);
        }
    }
    for (int t = 0; t < 4; ++t) {
        __syncthreads();
        const size_t tok = (size_t)blockIdx.x * 4 + t;
        {
            float4 x4 = ld4<ISBF>(x, tok * PK + e0);
            float v[4];
#pragma unroll
            for (int j = 0; j < 4; ++j) v[j] = f4c(x4, j) * gate[j] + bias[j];
            *(float4*)&resid[e0] = make_float4(v[0], v[1], v[2], v[3]);
            float s = v[0]+v[1]+v[2]+v[3], ss = v[0]*v[0]+v[1]*v[1]+v[2]*v[2]+v[3]*v[3];
#pragma unroll
            for (int m = 1; m < 32; m <<= 1) { s += __shfl_xor(s, m); ss += __shfl_xor(ss, m); }
            float mean = s * (1.f/128.f), var = ss * (1.f/128.f) - mean*mean;
            float rstd = rsqrtf(var + 1e-5f);
            float xn[4];
#pragma unroll
            for (int j = 0; j < 4; ++j) xn[j] = (v[j]-mean)*rstd*pgf[j]+pbf[j];
            *(float4*)&xnpad[(g0+1)*D + d0] = make_float4(xn[0],xn[1],xn[2],xn[3]);
        }
        __syncthreads();
        {
            const int h = tid;
            float acc[G];
#pragma unroll
            for (int g = 0; g < G; ++g) acc[g] = 0.f;
            for (int d4 = 0; d4 < D; d4 += 4) {
                float4 xr4[G + 2];
#pragma unroll
                for (int r = 0; r < G + 2; ++r) xr4[r] = *(const float4*)&xnpad[r * D + d4];
#pragma unroll
                for (int j = 0; j < 4; ++j) {
                    size_t o = (size_t)h * (D * 3) + (d4 + j) * 3;
                    float wk0 = ld1<ISBF>(w1raw, o), wk1 = ld1<ISBF>(w1raw, o+1), wk2 = ld1<ISBF>(w1raw, o+2);
#pragma unroll
                    for (int g = 0; g < G; ++g) {
                        acc[g] += f4c(xr4[g+0], j) * wk0;
                        acc[g] += f4c(xr4[g+1], j) * wk1;
                        acc[g] += f4c(xr4[g+2], j) * wk2;
                    }
                }
            }
            float b1h = ld1<ISBF>(b1, tid);
#pragma unroll
            for (int g = 0; g < G; ++g) {
                float m = acc[g] + b1h;
                midpadf[(g+1)*H + h] = 0.5f * m * (1.f + erff(m * 0.70710678118654752f));
            }
        }
        __syncthreads();
        {
            const int dd = tid & (D - 1);
            const int gh = tid >> 7;
            float acc2[4] = {0.f,0.f,0.f,0.f};
            for (int h4 = 0; h4 < H; h4 += 4) {
                float4 mr4[6];
#pragma unroll
                for (int r = 0; r < 6; ++r) mr4[r] = *(const float4*)&midpadf[(gh*4+r)*H + h4];
#pragma unroll
                for (int j = 0; j < 4; ++j) {
                    size_t o = (size_t)dd * (H * 3) + (h4 + j) * 3;
                    float wk0 = ld1<ISBF>(w2raw, o), wk1 = ld1<ISBF>(w2raw, o+1), wk2 = ld1<ISBF>(w2raw, o+2);
#pragma unroll
                    for (int jj = 0; jj < 4; ++jj) {
                        acc2[jj] += f4c(mr4[jj+0], j) * wk0;
                        acc2[jj] += f4c(mr4[jj+1], j) * wk1;
                        acc2[jj] += f4c(mr4[jj+2], j) * wk2;
                    }
                }
            }
            float b2d = ld1<ISBF>(b2, dd);
            float vz[4], s = 0.f, ss = 0.f;
#pragma unroll
            for (int j = 0; j < 4; ++j) {
                int e = (gh*4+j)*D + dd;
                float val = acc2[j] + b2d + resid[e];
                vz[j] = val; s += val; ss += val*val;
            }
#pragma unroll
            for (int m = 1; m < 64; m <<= 1) { s += __shfl_xor(s, m); ss += __shfl_xor(ss, m); }
            const int wid = tid >> 6;
            if ((tid & 63) == 0) { red[wid*2] = s; red[wid*2+1] = ss; }
            __syncthreads();
            float st = red[0]+red[2]+red[4]+red[6], sst = red[1]+red[3]+red[5]+red[7];
            float mean = st * (1.f/1024.f), var = sst * (1.f/1024.f) - mean*mean;
            float rstd = rsqrtf(var + 1e-5f);
#pragma unroll
            for (int j = 0; j < 4; ++j) {
                int e = (gh*4+j)*D + dd;
                zbuf[t][e] = (vz[j]-mean)*rstd*ld1<ISBF>(pack_g, e) + ld1<ISBF>(pack_b, e);
            }
        }
    }
    __syncthreads();
    {
        float accm[4][4];
#pragma unroll
        for (int t = 0; t < 4; ++t)
#pragma unroll
            for (int j = 0; j < 4; ++j) accm[t][j] = 0.f;
        for (int p4 = 0; p4 < PK; p4 += 4) {
            float4 z4[4];
#pragma unroll
            for (int t = 0; t < 4; ++t) z4[t] = *(const float4*)&zbuf[t][p4];
#pragma unroll
            for (int pp = 0; pp < 4; ++pp) {
                float4 w4 = ld4<ISBF>(Wm, (size_t)(p4 + pp) * DM + e0);
#pragma unroll
                for (int t = 0; t < 4; ++t) {
                    float zp = f4c(z4[t], pp);
                    accm[t][0] += zp * w4.x; accm[t][1] += zp * w4.y;
                    accm[t][2] += zp * w4.z; accm[t][3] += zp * w4.w;
                }
            }
        }
        float4 bm4 = ld4<ISBF>(bm, e0);
#pragma unroll
        for (int t = 0; t < 4; ++t) {
            const size_t tok = (size_t)blockIdx.x * 4 + t;
            st4<ISBF>(out, tok * DM + e0,
                      make_float4(accm[t][0]+bm4.x, accm[t][1]+bm4.y,
                                  accm[t][2]+bm4.z, accm[t][3]+bm4.w));
        }
    }
}

extern "C" void kernel_launch(void* const* d_in, const int* in_sizes, int n_in,
                              void* d_out, int out_size, void* d_ws, size_t ws_size,
                              hipStream_t stream) {
    const void* x   = d_in[0];
    const void* sg  = d_in[1];
    const void* sb  = d_in[2];
    const void* pg  = d_in[3];
    const void* pb  = d_in[4];
    const void* w1  = d_in[5];
    const void* b1  = d_in[6];
    const void* w2  = d_in[7];
    const void* b2  = d_in[8];
    const void* pkg = d_in[9];
    const void* pkb = d_in[10];
    const void* Wm  = d_in[11];
    const void* bm  = d_in[12];

    int* flag = (int*)d_ws;
    u16* base = (u16*)((char*)d_ws + 16);
    u16* w1b = base;                       // 98304 el
    u16* w2b = base + 98304;               // 98304 el
    u16* wmt = base + 196608;              // 1048576 el
    u16* zws = base + 196608 + 1048576;    // 16777216 el
    const size_t ws_needed = 16 + (size_t)(98304 + 98304 + 1048576 + 16777216) * sizeof(u16);

    detect_dtype<<<1, 256, 0, stream>>>(x, flag);

    if (ws_size >= ws_needed) {
        prep_mfma<true ><<<384, 256, 0, stream>>>(w1, w2, w1b, w2b, flag);
        prep_mfma<false><<<384, 256, 0, stream>>>(w1, w2, w1b, w2b, flag);
        trans_wm<true ><<<256, 256, 0, stream>>>(Wm, wmt, flag);
        trans_wm<false><<<256, 256, 0, stream>>>(Wm, wmt, flag);
        conv_fused<true ><<<NTOK / TPB, 256, 0, stream>>>(
            x, sg, sb, pg, pb, b1, b2, pkg, pkb, w1b, w2b, zws, flag);
        conv_fused<false><<<NTOK / TPB, 256, 0, stream>>>(
            x, sg, sb, pg, pb, b1, b2, pkg, pkb, w1b, w2b, zws, flag);
        gemm_out<true ><<<(NTOK / 128) * (DM / 128), 256, 0, stream>>>(zws, wmt, bm, d_out, flag);
        gemm_out<false><<<(NTOK / 128) * (DM / 128), 256, 0, stream>>>(zws, wmt, bm, d_out, flag);
    } else {
        slotconv_scalar<true ><<<NTOK / 4, 256, 0, stream>>>(
            x, sg, sb, pg, pb, w1, b1, w2, b2, pkg, pkb, Wm, bm, d_out, flag);
        slotconv_scalar<false><<<NTOK / 4, 256, 0, stream>>>(
            x, sg, sb, pg, pb, w1, b1, w2, b2, pkg, pkb, Wm, bm, d_out, flag);
    }
}